// Round 17
// baseline (1484.832 us; speedup 1.0000x reference)
//
#include <hip/hip_runtime.h>

#define S_LEN 1024
#define B_DIM 64
#define H_DIM 512
#define Y_SZ ((size_t)S_LEN * B_DIM * H_DIM)   // 33,554,432 elements

typedef float floatx2 __attribute__((ext_vector_type(2)));

// ---------------------------------------------------------------------------
// pk-GEMM: C[m,n] = sum_k A[m,k]*W[n,k] + bias[n]. Plain fp32 only (every
// exotic datapath — MFMA builtins/asm, fdot2 — fails on this toolchain,
// r6-r10/r15/r16). Two levers vs the r13 kernel (494 µs, LDS-pipe-bound at
// ~1139 LDS-cyc/wave-kt):
//  1) 8x8 thread tile, A rows read as b128: LDS instrs 128 -> 64 per
//     wave-kt AND wave-kt count halves -> LDS total ~327 µs.
//  2) floatx2 arithmetic -> v_pk_fma_f32 (2 FMA/instr): VALU 272 -> ~140 µs.
// Same staging layout + 2 barriers/kt as r13 (proven). Block owns 64 rows
// exclusively; all C stores after the last barrier -> in-place safe.
// Component selects macro-unrolled with literal .x/.y/.z/.w (no cndmask).
// Accumulation order per element unchanged (k ascending) -> bit-identical.
// ---------------------------------------------------------------------------
__global__ __launch_bounds__(512) void gemm_pk(
    const float* A, const float* __restrict__ W,
    const float* __restrict__ bias, float* C) {
  __shared__ float Bl[16][512];  // [k][n], staged transposed (r13 layout)
  __shared__ float Al[64][16];   // [r][k]

  const int tid = threadIdx.x;
  const int tr = tid >> 6;   // wave id 0..7: rows tr*8..+8 (uniform per wave)
  const int tc = tid & 63;   // cols tc*8..+8 (8 contiguous cols = 4 float2)
  const int brow = blockIdx.x * 64;

  floatx2 acc[8][4];
#pragma unroll
  for (int i = 0; i < 8; ++i)
#pragma unroll
    for (int j = 0; j < 4; ++j) acc[i][j] = (floatx2){0.f, 0.f};

  for (int kt = 0; kt < 32; ++kt) {
    // --- stage B transposed (r13 verbatim): W row tid, k-chunk kt*16
    {
      const float* wp = W + (size_t)tid * 512 + kt * 16;
      float4 w0 = *(const float4*)(wp + 0);
      float4 w1 = *(const float4*)(wp + 4);
      float4 w2 = *(const float4*)(wp + 8);
      float4 w3 = *(const float4*)(wp + 12);
      Bl[0][tid] = w0.x;  Bl[1][tid] = w0.y;  Bl[2][tid] = w0.z;  Bl[3][tid] = w0.w;
      Bl[4][tid] = w1.x;  Bl[5][tid] = w1.y;  Bl[6][tid] = w1.z;  Bl[7][tid] = w1.w;
      Bl[8][tid] = w2.x;  Bl[9][tid] = w2.y;  Bl[10][tid] = w2.z; Bl[11][tid] = w2.w;
      Bl[12][tid] = w3.x; Bl[13][tid] = w3.y; Bl[14][tid] = w3.z; Bl[15][tid] = w3.w;
    }
    // --- stage A (r13 verbatim): r = tid>>3, kk = (tid&7)*2
    {
      const int r = tid >> 3, kk = (tid & 7) * 2;
      const float* ap = A + (size_t)(brow + r) * 512 + kt * 16 + kk;
      Al[r][kk] = ap[0];
      Al[r][kk + 1] = ap[1];
    }
    __syncthreads();

#pragma unroll
    for (int kq = 0; kq < 4; ++kq) {
      const int kb = kq * 4;
      // A rows as b128 (wave-uniform address -> broadcast), 4 k's each
      float4 a0 = *(const float4*)&Al[tr * 8 + 0][kb];
      float4 a1 = *(const float4*)&Al[tr * 8 + 1][kb];
      float4 a2 = *(const float4*)&Al[tr * 8 + 2][kb];
      float4 a3 = *(const float4*)&Al[tr * 8 + 3][kb];
      float4 a4 = *(const float4*)&Al[tr * 8 + 4][kb];
      float4 a5 = *(const float4*)&Al[tr * 8 + 5][kb];
      float4 a6 = *(const float4*)&Al[tr * 8 + 6][kb];
      float4 a7 = *(const float4*)&Al[tr * 8 + 7][kb];

#define PKSTEP(KOFF, CMP)                                                     \
      {                                                                       \
        float4 bq0 = *(const float4*)&Bl[kb + KOFF][tc * 8];                  \
        float4 bq1 = *(const float4*)&Bl[kb + KOFF][tc * 8 + 4];              \
        floatx2 b0 = (floatx2){bq0.x, bq0.y};                                 \
        floatx2 b1 = (floatx2){bq0.z, bq0.w};                                 \
        floatx2 b2 = (floatx2){bq1.x, bq1.y};                                 \
        floatx2 b3 = (floatx2){bq1.z, bq1.w};                                 \
        floatx2 v;                                                            \
        v = (floatx2){a0.CMP, a0.CMP};                                        \
        acc[0][0] += v * b0; acc[0][1] += v * b1;                             \
        acc[0][2] += v * b2; acc[0][3] += v * b3;                             \
        v = (floatx2){a1.CMP, a1.CMP};                                        \
        acc[1][0] += v * b0; acc[1][1] += v * b1;                             \
        acc[1][2] += v * b2; acc[1][3] += v * b3;                             \
        v = (floatx2){a2.CMP, a2.CMP};                                        \
        acc[2][0] += v * b0; acc[2][1] += v * b1;                             \
        acc[2][2] += v * b2; acc[2][3] += v * b3;                             \
        v = (floatx2){a3.CMP, a3.CMP};                                        \
        acc[3][0] += v * b0; acc[3][1] += v * b1;                             \
        acc[3][2] += v * b2; acc[3][3] += v * b3;                             \
        v = (floatx2){a4.CMP, a4.CMP};                                        \
        acc[4][0] += v * b0; acc[4][1] += v * b1;                             \
        acc[4][2] += v * b2; acc[4][3] += v * b3;                             \
        v = (floatx2){a5.CMP, a5.CMP};                                        \
        acc[5][0] += v * b0; acc[5][1] += v * b1;                             \
        acc[5][2] += v * b2; acc[5][3] += v * b3;                             \
        v = (floatx2){a6.CMP, a6.CMP};                                        \
        acc[6][0] += v * b0; acc[6][1] += v * b1;                             \
        acc[6][2] += v * b2; acc[6][3] += v * b3;                             \
        v = (floatx2){a7.CMP, a7.CMP};                                        \
        acc[7][0] += v * b0; acc[7][1] += v * b1;                             \
        acc[7][2] += v * b2; acc[7][3] += v * b3;                             \
      }
      PKSTEP(0, x)
      PKSTEP(1, y)
      PKSTEP(2, z)
      PKSTEP(3, w)
#undef PKSTEP
    }
    __syncthreads();
  }

  // Epilogue: all staging (A) reads complete block-wide -> safe to write C.
#pragma unroll
  for (int i = 0; i < 8; ++i) {
    const int row = brow + tr * 8 + i;
    const int c0 = tc * 8;
    float4 o0, o1;
    o0.x = acc[i][0].x + bias[c0 + 0];
    o0.y = acc[i][0].y + bias[c0 + 1];
    o0.z = acc[i][1].x + bias[c0 + 2];
    o0.w = acc[i][1].y + bias[c0 + 3];
    o1.x = acc[i][2].x + bias[c0 + 4];
    o1.y = acc[i][2].y + bias[c0 + 5];
    o1.z = acc[i][3].x + bias[c0 + 6];
    o1.w = acc[i][3].y + bias[c0 + 7];
    *(float4*)&C[(size_t)row * 512 + c0] = o0;
    *(float4*)&C[(size_t)row * 512 + c0 + 4] = o1;
  }
}

// ---------------------------------------------------------------------------
// DPP wave64 sum-reduce helper (r14 EXACT, hardware-proven).
// ---------------------------------------------------------------------------
__device__ static inline float dpp_add_step(float v, const int ctrl) {
  int perm;
  switch (ctrl) {  // ctrl is compile-time constant at each call site
    case 0xB1:  perm = __builtin_amdgcn_update_dpp(0, __builtin_bit_cast(int, v), 0xB1,  0xF, 0xF, true); break;
    case 0x4E:  perm = __builtin_amdgcn_update_dpp(0, __builtin_bit_cast(int, v), 0x4E,  0xF, 0xF, true); break;
    case 0x141: perm = __builtin_amdgcn_update_dpp(0, __builtin_bit_cast(int, v), 0x141, 0xF, 0xF, true); break;
    case 0x140: perm = __builtin_amdgcn_update_dpp(0, __builtin_bit_cast(int, v), 0x140, 0xF, 0xF, true); break;
    case 0x142: perm = __builtin_amdgcn_update_dpp(0, __builtin_bit_cast(int, v), 0x142, 0xF, 0xF, true); break;
    default:    perm = __builtin_amdgcn_update_dpp(0, __builtin_bit_cast(int, v), 0x143, 0xF, 0xF, true); break;
  }
  return v + __builtin_bit_cast(float, perm);
}

// ---------------------------------------------------------------------------
// Scan (r14 EXACT, hardware-proven ~174 µs): depth-8 prefetch ring, one wave
// per batch row, DPP reduction, relu6, in-place safe.
// ---------------------------------------------------------------------------
__global__ __launch_bounds__(64) void scan_ln_relu6(
    const float* lin, const float* __restrict__ rec,
    const float* __restrict__ gam, const float* __restrict__ bet,
    float* y, float* __restrict__ hlast) {
  const int b = blockIdx.x;
  const int lane = threadIdx.x;
  const int e0 = lane * 8;

  float rf[8], gf[8], bp[8], h[8];
#pragma unroll
  for (int i = 0; i < 8; ++i) {
    rf[i] = rec[e0 + i];
    gf[i] = gam[e0 + i];
    bp[i] = bet[e0 + i];
    h[i] = 0.0f;
  }

  const size_t BH = (size_t)B_DIM * H_DIM;
  const size_t base = (size_t)b * H_DIM + e0;

  float4 pa[8], pb[8];  // prefetch ring: row s0+k held in pa[k]/pb[k]
#pragma unroll
  for (int k = 0; k < 8; ++k) {
    pa[k] = *(const float4*)&lin[base + (size_t)k * BH];
    pb[k] = *(const float4*)&lin[base + (size_t)k * BH + 4];
  }

  for (int s0 = 0; s0 < S_LEN; s0 += 8) {
#pragma unroll
    for (int k = 0; k < 8; ++k) {   // k compile-time after unroll
      const int s = s0 + k;
      float hv[8];
      hv[0] = pa[k].x + rf[0] * h[0]; hv[1] = pa[k].y + rf[1] * h[1];
      hv[2] = pa[k].z + rf[2] * h[2]; hv[3] = pa[k].w + rf[3] * h[3];
      hv[4] = pb[k].x + rf[4] * h[4]; hv[5] = pb[k].y + rf[5] * h[5];
      hv[6] = pb[k].z + rf[6] * h[6]; hv[7] = pb[k].w + rf[7] * h[7];
      if (s + 8 < S_LEN) {  // issue prefetch for s+8 (consumed 8 steps later)
        pa[k] = *(const float4*)&lin[base + (size_t)(s + 8) * BH];
        pb[k] = *(const float4*)&lin[base + (size_t)(s + 8) * BH + 4];
      }
      float s1 = 0.0f, s2 = 0.0f;
#pragma unroll
      for (int i = 0; i < 8; ++i) {
        s1 += hv[i];
        s2 += hv[i] * hv[i];
      }
      // --- interleaved DPP butterfly: full 64-lane sums of s1, s2 ---
      s1 = dpp_add_step(s1, 0xB1);  s2 = dpp_add_step(s2, 0xB1);   // quad xor1
      s1 = dpp_add_step(s1, 0x4E);  s2 = dpp_add_step(s2, 0x4E);   // quad xor2
      s1 = dpp_add_step(s1, 0x141); s2 = dpp_add_step(s2, 0x141);  // half_mirror
      s1 = dpp_add_step(s1, 0x140); s2 = dpp_add_step(s2, 0x140);  // row_mirror
      s1 = dpp_add_step(s1, 0x142); s2 = dpp_add_step(s2, 0x142);  // bcast15
      s1 = dpp_add_step(s1, 0x143); s2 = dpp_add_step(s2, 0x143);  // bcast31
      const float S1 = __builtin_bit_cast(float,
          __builtin_amdgcn_readlane(__builtin_bit_cast(int, s1), 63));
      const float S2 = __builtin_bit_cast(float,
          __builtin_amdgcn_readlane(__builtin_bit_cast(int, s2), 63));
      const float mu = S1 * (1.0f / 512.0f);
      const float var = S2 * (1.0f / 512.0f) - mu * mu;  // biased variance
      const float rs = rsqrtf(var + 1e-6f);
      float4 o0, o1;
      float v;
      v = (hv[0] - mu) * rs * gf[0] + bp[0]; v = fminf(fmaxf(v, 0.0f), 6.0f); h[0] = v; o0.x = v;
      v = (hv[1] - mu) * rs * gf[1] + bp[1]; v = fminf(fmaxf(v, 0.0f), 6.0f); h[1] = v; o0.y = v;
      v = (hv[2] - mu) * rs * gf[2] + bp[2]; v = fminf(fmaxf(v, 0.0f), 6.0f); h[2] = v; o0.z = v;
      v = (hv[3] - mu) * rs * gf[3] + bp[3]; v = fminf(fmaxf(v, 0.0f), 6.0f); h[3] = v; o0.w = v;
      v = (hv[4] - mu) * rs * gf[4] + bp[4]; v = fminf(fmaxf(v, 0.0f), 6.0f); h[4] = v; o1.x = v;
      v = (hv[5] - mu) * rs * gf[5] + bp[5]; v = fminf(fmaxf(v, 0.0f), 6.0f); h[5] = v; o1.y = v;
      v = (hv[6] - mu) * rs * gf[6] + bp[6]; v = fminf(fmaxf(v, 0.0f), 6.0f); h[6] = v; o1.z = v;
      v = (hv[7] - mu) * rs * gf[7] + bp[7]; v = fminf(fmaxf(v, 0.0f), 6.0f); h[7] = v; o1.w = v;
      float* yp = y + base + (size_t)s * BH;
      *(float4*)yp = o0;
      *(float4*)(yp + 4) = o1;
    }
  }

  float* hp = hlast + b * 1024 + e0;
  float4 h0; h0.x = h[0]; h0.y = h[1]; h0.z = h[2]; h0.w = h[3];
  float4 h1; h1.x = h[4]; h1.y = h[5]; h1.z = h[6]; h1.w = h[7];
  *(float4*)hp = h0;
  *(float4*)(hp + 4) = h1;
}

extern "C" void kernel_launch(void* const* d_in, const int* in_sizes, int n_in,
                              void* d_out, int out_size, void* d_ws, size_t ws_size,
                              hipStream_t stream) {
  const float* x   = (const float*)d_in[0];
  const float* W0  = (const float*)d_in[1];
  const float* b0  = (const float*)d_in[2];
  const float* r0  = (const float*)d_in[3];
  const float* g0  = (const float*)d_in[4];
  const float* be0 = (const float*)d_in[5];
  const float* W1  = (const float*)d_in[6];
  const float* b1  = (const float*)d_in[7];
  const float* r1  = (const float*)d_in[8];
  const float* g1  = (const float*)d_in[9];
  const float* be1 = (const float*)d_in[10];

  float* out = (float*)d_out;
  float* R   = out;              // y-region: lin0 -> y0 -> lin1 -> y, in place
  float* hl0 = out + Y_SZ;       // hiddens flat: out[Y_SZ + b*1024 + l*512 + h]
  float* hl1 = out + Y_SZ + 512;
  (void)d_ws; (void)ws_size; (void)in_sizes; (void)n_in; (void)out_size;

  // layer 0
  gemm_pk<<<1024, 512, 0, stream>>>(x, W0, b0, R);
  scan_ln_relu6<<<64, 64, 0, stream>>>(R, r0, g0, be0, R, hl0);
  // layer 1 (reads y0 from R, writes lin1 over R; in-place-safe by design)
  gemm_pk<<<1024, 512, 0, stream>>>(R, W1, b1, R);
  scan_ln_relu6<<<64, 64, 0, stream>>>(R, r1, g1, be1, R, hl1);
}

// Round 18
// 1412.350 us; speedup vs baseline: 1.0513x; 1.0513x over previous
//
#include <hip/hip_runtime.h>

#define S_LEN 1024
#define B_DIM 64
#define H_DIM 512
#define Y_SZ ((size_t)S_LEN * B_DIM * H_DIM)   // 33,554,432 elements

// ---------------------------------------------------------------------------
// 8x8 GEMM: C[m,n] = sum_k A[m,k]*W[n,k] + bias[n]. Plain fp32 (all exotic
// datapaths fail on this toolchain: r6-r10/r15/r16).
// vs r13 (494 µs, LDS-bound at 1139 cyc/wave-kt): 8 rows x 8 cols per thread
//  -> LDS 64 b128/wave-kt = 768 cyc (A: 8 b128-broadcast x 4 kq; B: 2 b128
//     x 16 k), same FMA count.
// vs r17 (606 µs): B cols split {tc*4, 256+tc*4} = 16B lane-stride ->
//     conflict-free (r17's tc*8 = 32B stride was a 4-way conflict, 3.4e7).
// VGPR budget: deliberately ~110 (m69: flat ceiling 64<v<=128 -> 16
// waves/CU); r13's 64-VGPR config can't hold an 8-row A ring.
// Same staging + 2 barriers/kt as r13. Block owns 64 rows exclusively; all C
// stores after the last barrier -> in-place safe (C may alias A).
// Per-element k-accumulation order identical to r13 -> bit-identical output.
// ---------------------------------------------------------------------------
__global__ __launch_bounds__(512) void gemm_8x8(
    const float* A, const float* __restrict__ W,
    const float* __restrict__ bias, float* C) {
  __shared__ float Bl[16][512];  // [k][n], staged transposed (r13 layout)
  __shared__ float Al[64][16];   // [r][k]

  const int tid = threadIdx.x;
  const int tr = tid >> 6;   // wave id 0..7: rows tr*8..+8 (uniform per wave)
  const int tc = tid & 63;   // cols tc*4 and 256+tc*4
  const int brow = blockIdx.x * 64;

  float4 acc0[8], acc1[8];
#pragma unroll
  for (int i = 0; i < 8; ++i) {
    acc0[i] = make_float4(0.f, 0.f, 0.f, 0.f);
    acc1[i] = make_float4(0.f, 0.f, 0.f, 0.f);
  }

  for (int kt = 0; kt < 32; ++kt) {
    // --- stage B transposed (r13 verbatim): W row tid, k-chunk kt*16
    {
      const float* wp = W + (size_t)tid * 512 + kt * 16;
      float4 w0 = *(const float4*)(wp + 0);
      float4 w1 = *(const float4*)(wp + 4);
      float4 w2 = *(const float4*)(wp + 8);
      float4 w3 = *(const float4*)(wp + 12);
      Bl[0][tid] = w0.x;  Bl[1][tid] = w0.y;  Bl[2][tid] = w0.z;  Bl[3][tid] = w0.w;
      Bl[4][tid] = w1.x;  Bl[5][tid] = w1.y;  Bl[6][tid] = w1.z;  Bl[7][tid] = w1.w;
      Bl[8][tid] = w2.x;  Bl[9][tid] = w2.y;  Bl[10][tid] = w2.z; Bl[11][tid] = w2.w;
      Bl[12][tid] = w3.x; Bl[13][tid] = w3.y; Bl[14][tid] = w3.z; Bl[15][tid] = w3.w;
    }
    // --- stage A (r13 verbatim): r = tid>>3, kk = (tid&7)*2
    {
      const int r = tid >> 3, kk = (tid & 7) * 2;
      const float* ap = A + (size_t)(brow + r) * 512 + kt * 16 + kk;
      Al[r][kk] = ap[0];
      Al[r][kk + 1] = ap[1];
    }
    __syncthreads();

#pragma unroll
    for (int kq = 0; kq < 4; ++kq) {
      const int kb = kq * 4;
      float4 a[8];
#pragma unroll
      for (int i = 0; i < 8; ++i)
        a[i] = *(const float4*)&Al[tr * 8 + i][kb];  // wave-uniform broadcast

#define KSTEP(KK, CMP)                                                        \
      {                                                                       \
        float4 b0 = *(const float4*)&Bl[kb + KK][tc * 4];                     \
        float4 b1 = *(const float4*)&Bl[kb + KK][256 + tc * 4];               \
        _Pragma("unroll")                                                     \
        for (int i = 0; i < 8; ++i) {                                         \
          const float av = a[i].CMP;                                          \
          acc0[i].x += av * b0.x; acc0[i].y += av * b0.y;                     \
          acc0[i].z += av * b0.z; acc0[i].w += av * b0.w;                     \
          acc1[i].x += av * b1.x; acc1[i].y += av * b1.y;                     \
          acc1[i].z += av * b1.z; acc1[i].w += av * b1.w;                     \
        }                                                                     \
      }
      KSTEP(0, x)
      KSTEP(1, y)
      KSTEP(2, z)
      KSTEP(3, w)
#undef KSTEP
    }
    __syncthreads();
  }

  // Epilogue: all staging (A) reads complete block-wide -> safe to write C.
#pragma unroll
  for (int i = 0; i < 8; ++i) {
    const int row = brow + tr * 8 + i;
    const int c0 = tc * 4;
    float4 o0, o1;
    o0.x = acc0[i].x + bias[c0 + 0];
    o0.y = acc0[i].y + bias[c0 + 1];
    o0.z = acc0[i].z + bias[c0 + 2];
    o0.w = acc0[i].w + bias[c0 + 3];
    o1.x = acc1[i].x + bias[256 + c0 + 0];
    o1.y = acc1[i].y + bias[256 + c0 + 1];
    o1.z = acc1[i].z + bias[256 + c0 + 2];
    o1.w = acc1[i].w + bias[256 + c0 + 3];
    *(float4*)&C[(size_t)row * 512 + c0] = o0;
    *(float4*)&C[(size_t)row * 512 + 256 + c0] = o1;
  }
}

// ---------------------------------------------------------------------------
// DPP wave64 sum-reduce helper (r14 EXACT, hardware-proven).
// ---------------------------------------------------------------------------
__device__ static inline float dpp_add_step(float v, const int ctrl) {
  int perm;
  switch (ctrl) {  // ctrl is compile-time constant at each call site
    case 0xB1:  perm = __builtin_amdgcn_update_dpp(0, __builtin_bit_cast(int, v), 0xB1,  0xF, 0xF, true); break;
    case 0x4E:  perm = __builtin_amdgcn_update_dpp(0, __builtin_bit_cast(int, v), 0x4E,  0xF, 0xF, true); break;
    case 0x141: perm = __builtin_amdgcn_update_dpp(0, __builtin_bit_cast(int, v), 0x141, 0xF, 0xF, true); break;
    case 0x140: perm = __builtin_amdgcn_update_dpp(0, __builtin_bit_cast(int, v), 0x140, 0xF, 0xF, true); break;
    case 0x142: perm = __builtin_amdgcn_update_dpp(0, __builtin_bit_cast(int, v), 0x142, 0xF, 0xF, true); break;
    default:    perm = __builtin_amdgcn_update_dpp(0, __builtin_bit_cast(int, v), 0x143, 0xF, 0xF, true); break;
  }
  return v + __builtin_bit_cast(float, perm);
}

// ---------------------------------------------------------------------------
// Scan (r14 EXACT, hardware-proven ~174 µs): depth-8 prefetch ring, one wave
// per batch row, DPP reduction, relu6, in-place safe.
// ---------------------------------------------------------------------------
__global__ __launch_bounds__(64) void scan_ln_relu6(
    const float* lin, const float* __restrict__ rec,
    const float* __restrict__ gam, const float* __restrict__ bet,
    float* y, float* __restrict__ hlast) {
  const int b = blockIdx.x;
  const int lane = threadIdx.x;
  const int e0 = lane * 8;

  float rf[8], gf[8], bp[8], h[8];
#pragma unroll
  for (int i = 0; i < 8; ++i) {
    rf[i] = rec[e0 + i];
    gf[i] = gam[e0 + i];
    bp[i] = bet[e0 + i];
    h[i] = 0.0f;
  }

  const size_t BH = (size_t)B_DIM * H_DIM;
  const size_t base = (size_t)b * H_DIM + e0;

  float4 pa[8], pb[8];  // prefetch ring: row s0+k held in pa[k]/pb[k]
#pragma unroll
  for (int k = 0; k < 8; ++k) {
    pa[k] = *(const float4*)&lin[base + (size_t)k * BH];
    pb[k] = *(const float4*)&lin[base + (size_t)k * BH + 4];
  }

  for (int s0 = 0; s0 < S_LEN; s0 += 8) {
#pragma unroll
    for (int k = 0; k < 8; ++k) {   // k compile-time after unroll
      const int s = s0 + k;
      float hv[8];
      hv[0] = pa[k].x + rf[0] * h[0]; hv[1] = pa[k].y + rf[1] * h[1];
      hv[2] = pa[k].z + rf[2] * h[2]; hv[3] = pa[k].w + rf[3] * h[3];
      hv[4] = pb[k].x + rf[4] * h[4]; hv[5] = pb[k].y + rf[5] * h[5];
      hv[6] = pb[k].z + rf[6] * h[6]; hv[7] = pb[k].w + rf[7] * h[7];
      if (s + 8 < S_LEN) {  // issue prefetch for s+8 (consumed 8 steps later)
        pa[k] = *(const float4*)&lin[base + (size_t)(s + 8) * BH];
        pb[k] = *(const float4*)&lin[base + (size_t)(s + 8) * BH + 4];
      }
      float s1 = 0.0f, s2 = 0.0f;
#pragma unroll
      for (int i = 0; i < 8; ++i) {
        s1 += hv[i];
        s2 += hv[i] * hv[i];
      }
      // --- interleaved DPP butterfly: full 64-lane sums of s1, s2 ---
      s1 = dpp_add_step(s1, 0xB1);  s2 = dpp_add_step(s2, 0xB1);   // quad xor1
      s1 = dpp_add_step(s1, 0x4E);  s2 = dpp_add_step(s2, 0x4E);   // quad xor2
      s1 = dpp_add_step(s1, 0x141); s2 = dpp_add_step(s2, 0x141);  // half_mirror
      s1 = dpp_add_step(s1, 0x140); s2 = dpp_add_step(s2, 0x140);  // row_mirror
      s1 = dpp_add_step(s1, 0x142); s2 = dpp_add_step(s2, 0x142);  // bcast15
      s1 = dpp_add_step(s1, 0x143); s2 = dpp_add_step(s2, 0x143);  // bcast31
      const float S1 = __builtin_bit_cast(float,
          __builtin_amdgcn_readlane(__builtin_bit_cast(int, s1), 63));
      const float S2 = __builtin_bit_cast(float,
          __builtin_amdgcn_readlane(__builtin_bit_cast(int, s2), 63));
      const float mu = S1 * (1.0f / 512.0f);
      const float var = S2 * (1.0f / 512.0f) - mu * mu;  // biased variance
      const float rs = rsqrtf(var + 1e-6f);
      float4 o0, o1;
      float v;
      v = (hv[0] - mu) * rs * gf[0] + bp[0]; v = fminf(fmaxf(v, 0.0f), 6.0f); h[0] = v; o0.x = v;
      v = (hv[1] - mu) * rs * gf[1] + bp[1]; v = fminf(fmaxf(v, 0.0f), 6.0f); h[1] = v; o0.y = v;
      v = (hv[2] - mu) * rs * gf[2] + bp[2]; v = fminf(fmaxf(v, 0.0f), 6.0f); h[2] = v; o0.z = v;
      v = (hv[3] - mu) * rs * gf[3] + bp[3]; v = fminf(fmaxf(v, 0.0f), 6.0f); h[3] = v; o0.w = v;
      v = (hv[4] - mu) * rs * gf[4] + bp[4]; v = fminf(fmaxf(v, 0.0f), 6.0f); h[4] = v; o1.x = v;
      v = (hv[5] - mu) * rs * gf[5] + bp[5]; v = fminf(fmaxf(v, 0.0f), 6.0f); h[5] = v; o1.y = v;
      v = (hv[6] - mu) * rs * gf[6] + bp[6]; v = fminf(fmaxf(v, 0.0f), 6.0f); h[6] = v; o1.z = v;
      v = (hv[7] - mu) * rs * gf[7] + bp[7]; v = fminf(fmaxf(v, 0.0f), 6.0f); h[7] = v; o1.w = v;
      float* yp = y + base + (size_t)s * BH;
      *(float4*)yp = o0;
      *(float4*)(yp + 4) = o1;
    }
  }

  float* hp = hlast + b * 1024 + e0;
  float4 h0; h0.x = h[0]; h0.y = h[1]; h0.z = h[2]; h0.w = h[3];
  float4 h1; h1.x = h[4]; h1.y = h[5]; h1.z = h[6]; h1.w = h[7];
  *(float4*)hp = h0;
  *(float4*)(hp + 4) = h1;
}

extern "C" void kernel_launch(void* const* d_in, const int* in_sizes, int n_in,
                              void* d_out, int out_size, void* d_ws, size_t ws_size,
                              hipStream_t stream) {
  const float* x   = (const float*)d_in[0];
  const float* W0  = (const float*)d_in[1];
  const float* b0  = (const float*)d_in[2];
  const float* r0  = (const float*)d_in[3];
  const float* g0  = (const float*)d_in[4];
  const float* be0 = (const float*)d_in[5];
  const float* W1  = (const float*)d_in[6];
  const float* b1  = (const float*)d_in[7];
  const float* r1  = (const float*)d_in[8];
  const float* g1  = (const float*)d_in[9];
  const float* be1 = (const float*)d_in[10];

  float* out = (float*)d_out;
  float* R   = out;              // y-region: lin0 -> y0 -> lin1 -> y, in place
  float* hl0 = out + Y_SZ;       // hiddens flat: out[Y_SZ + b*1024 + l*512 + h]
  float* hl1 = out + Y_SZ + 512;
  (void)d_ws; (void)ws_size; (void)in_sizes; (void)n_in; (void)out_size;

  // layer 0
  gemm_8x8<<<1024, 512, 0, stream>>>(x, W0, b0, R);
  scan_ln_relu6<<<64, 64, 0, stream>>>(R, r0, g0, be0, R, hl0);
  // layer 1 (reads y0 from R, writes lin1 over R; in-place-safe by design)
  gemm_8x8<<<1024, 512, 0, stream>>>(R, W1, b1, R);
  scan_ln_relu6<<<64, 64, 0, stream>>>(R, r1, g1, be1, R, hl1);
}